// Round 2
// baseline (161.140 us; speedup 1.0000x reference)
//
#include <hip/hip_runtime.h>
#include <hip/hip_bf16.h>

#define BB 16
#define SS 512
#define HH 768
#define RR 8
#define DD 512
#define CC 27
#define WW 256

// ---------------------------------------------------------------------------
// ws layout:
//   first_idx : int[BB*WW]            @ byte 0        (16 KB)
//   h_rel     : float[BB*RR*DD]       @ byte 16384    (256 KB)
//   h_word    : float[BB*WW*DD]       @ byte 278528   (8 MB)
// ---------------------------------------------------------------------------

__device__ __forceinline__ unsigned short f32_to_bf16_rne(float v) {
    unsigned int u = __float_as_uint(v);
    unsigned int r = u + 0x7fffu + ((u >> 16) & 1u);
    return (unsigned short)(r >> 16);
}

// K2: first-occurrence index per (b, word). word_ids sorted along s.
__global__ void k_first_idx(const int* __restrict__ word_ids,
                            int* __restrict__ first_idx) {
    int b = blockIdx.x;
    int t = threadIdx.x;            // 512 threads
    if (t < WW) first_idx[b * WW + t] = -1;
    __syncthreads();
    int wid  = word_ids[b * SS + t];
    int prev = (t == 0) ? -1 : word_ids[b * SS + t - 1];
    if (wid != prev) first_idx[b * WW + wid] = t;   // unique per (b,wid)
}

// K1: rel_logits[b,s] = dot(hidden[b,s,:], w_rel) + b_rel
__global__ __launch_bounds__(256) void k_rel_logits(
    const float4* __restrict__ hid4, const float4* __restrict__ wrel4,
    const float* __restrict__ b_rel, float* __restrict__ out) {
    int t = threadIdx.x;
    int lane = t & 63;
    int row = blockIdx.x * 4 + (t >> 6);     // one wave per row
    int base = row * (HH / 4);               // 192 float4 per row
    float acc = 0.f;
#pragma unroll
    for (int j = 0; j < 3; ++j) {
        float4 v = hid4[base + j * 64 + lane];
        float4 w = wrel4[j * 64 + lane];
        acc += v.x * w.x + v.y * w.y + v.z * w.z + v.w * w.w;
    }
#pragma unroll
    for (int off = 32; off > 0; off >>= 1) acc += __shfl_xor(acc, off, 64);
    if (lane == 0) out[row] = acc + b_rel[0];
}

// K3: h_rel[b,r,d] = sum_h hidden[b, relpos[b,r], h] * w1[HH+h, d]
__global__ __launch_bounds__(256) void k_h_rel(
    const float* __restrict__ hidden, const int* __restrict__ relpos,
    const float* __restrict__ w1, float* __restrict__ h_rel) {
    int dc = blockIdx.x;   // 0..7 : 64-wide d chunk
    int b  = blockIdx.y;   // 0..15
    int t  = threadIdx.x;  // 256
    __shared__ float hid_s[RR][HH];
    for (int idx4 = t; idx4 < RR * (HH / 4); idx4 += 256) {
        int rr = idx4 / (HH / 4);
        int h4 = idx4 % (HH / 4);
        int pos = relpos[b * RR + rr];
        float4 v = ((const float4*)hidden)[(size_t)(b * SS + pos) * (HH / 4) + h4];
        ((float4*)&hid_s[rr][0])[h4] = v;
    }
    __syncthreads();
    int d = dc * 64 + (t & 63);
    int g = t >> 6;                 // handles r = g and g+4
    float acc0 = 0.f, acc1 = 0.f;
    const float* w1b = w1 + (size_t)HH * DD;   // bottom half rows
#pragma unroll 8
    for (int h = 0; h < HH; ++h) {
        float wv = w1b[(size_t)h * DD + d];
        acc0 = fmaf(hid_s[g][h],     wv, acc0);
        acc1 = fmaf(hid_s[g + 4][h], wv, acc1);
    }
    h_rel[(b * RR + g) * DD + d]     = acc0;
    h_rel[(b * RR + g + 4) * DD + d] = acc1;
}

// K4: h_word = first_hidden @ w1[:HH]   (M=4096 gathered rows, N=512, K=768)
// 64x64 tile, BK=16, 256 threads, 4x4 per thread, f32 vector FMA.
__global__ __launch_bounds__(256) void k_h_word(
    const float* __restrict__ hidden, const int* __restrict__ first_idx,
    const float* __restrict__ w1, float* __restrict__ h_word) {
    int nt = blockIdx.x;   // 0..7
    int mt = blockIdx.y;   // 0..63
    int t  = threadIdx.x;
    __shared__ float a_s[16][68];   // [k][m]
    __shared__ float b_s[16][68];   // [k][n]
    int tm = t & 15, tn = t >> 4;
    // A staging indices (fixed per thread)
    int am  = t >> 2;
    int ak4 = (t & 3) * 4;
    int mrow = mt * 64 + am;
    int bb = mrow >> 8, w = mrow & 255;
    int src = first_idx[bb * WW + w];
    const float* arow = (src >= 0) ? (hidden + (size_t)(bb * SS + src) * HH) : nullptr;
    // B staging indices
    int bk  = t >> 4;
    int bn4 = (t & 15) * 4;
    int ncol0 = nt * 64;
    float acc[4][4] = {};
    for (int kt = 0; kt < HH / 16; ++kt) {
        float4 av = make_float4(0.f, 0.f, 0.f, 0.f);
        if (arow) av = *(const float4*)(arow + kt * 16 + ak4);
        a_s[ak4 + 0][am] = av.x;
        a_s[ak4 + 1][am] = av.y;
        a_s[ak4 + 2][am] = av.z;
        a_s[ak4 + 3][am] = av.w;
        float4 bv = *(const float4*)(w1 + (size_t)(kt * 16 + bk) * DD + ncol0 + bn4);
        *(float4*)&b_s[bk][bn4] = bv;
        __syncthreads();
#pragma unroll
        for (int k = 0; k < 16; ++k) {
            float4 a  = *(const float4*)&a_s[k][tm * 4];
            float4 bv2 = *(const float4*)&b_s[k][tn * 4];
            float af[4] = {a.x, a.y, a.z, a.w};
            float bf[4] = {bv2.x, bv2.y, bv2.z, bv2.w};
#pragma unroll
            for (int i = 0; i < 4; ++i) {
#pragma unroll
                for (int j = 0; j < 4; ++j)
                    acc[i][j] = fmaf(af[i], bf[j], acc[i][j]);
            }
        }
        __syncthreads();
    }
#pragma unroll
    for (int i = 0; i < 4; ++i) {
        int m = mt * 64 + tm * 4 + i;
        float4 o = make_float4(acc[i][0], acc[i][1], acc[i][2], acc[i][3]);
        *(float4*)&h_word[(size_t)m * DD + ncol0 + tn * 4] = o;
    }
}

// K5: role_logits[b,r,w,c] = relu(h_word[b,w,:]+h_rel[b,r,:]+b1) @ w2 + b2
// block = (b, tile of 8 w) ; 256 thr ; per thread 4 (same-w) rows x 2 cols.
__global__ __launch_bounds__(256) void k_role(
    const float* __restrict__ h_word, const float* __restrict__ h_rel,
    const float* __restrict__ w2, const float* __restrict__ b1,
    const float* __restrict__ b2, float* __restrict__ out_role) {
    int wt = blockIdx.x;   // 0..31
    int b  = blockIdx.y;   // 0..15
    int t  = threadIdx.x;  // 256
    __shared__ float hw_s[8][516];
    __shared__ float hr_s[8][516];
    __shared__ unsigned short w2_s[512][32];   // bf16, padded to 32 cols
    // stage h_word tile (+b1 folded in)
    for (int idx = t; idx < 8 * 128; idx += 256) {
        int wl = idx >> 7;
        int d4 = (idx & 127) * 4;
        float4 v = *(const float4*)&h_word[(size_t)((b * WW + wt * 8 + wl)) * DD + d4];
        float4 bv = *(const float4*)&b1[d4];
        hw_s[wl][d4 + 0] = v.x + bv.x;
        hw_s[wl][d4 + 1] = v.y + bv.y;
        hw_s[wl][d4 + 2] = v.z + bv.z;
        hw_s[wl][d4 + 3] = v.w + bv.w;
    }
    // stage h_rel rows
    for (int idx = t; idx < 8 * 128; idx += 256) {
        int rl = idx >> 7;
        int d4 = (idx & 127) * 4;
        float4 v = *(const float4*)&h_rel[(size_t)(b * RR + rl) * DD + d4];
        hr_s[rl][d4 + 0] = v.x;
        hr_s[rl][d4 + 1] = v.y;
        hr_s[rl][d4 + 2] = v.z;
        hr_s[rl][d4 + 3] = v.w;
    }
    // stage w2 as bf16 (rounded), pad cols 27->32 with zeros
    for (int idx = t; idx < 512 * 32; idx += 256) {
        int d = idx >> 5, c = idx & 31;
        float v = (c < CC) ? w2[d * CC + c] : 0.f;
        w2_s[d][c] = f32_to_bf16_rne(v);
    }
    __syncthreads();
    int q  = t & 15;          // quad id: rows q*4 .. q*4+3
    int cg = t >> 4;          // 0..15 -> cols cg*2, cg*2+1
    int wl = q >> 1;
    int rbase = (q & 1) * 4;
    float acc[4][2] = {};
#pragma unroll 2
    for (int d = 0; d < 512; ++d) {
        float hw = hw_s[wl][d];
        unsigned int u = ((const unsigned int*)&w2_s[d][0])[cg];
        float w2lo = __uint_as_float(u << 16);
        float w2hi = __uint_as_float(u & 0xffff0000u);
#pragma unroll
        for (int j = 0; j < 4; ++j) {
            float hm = fmaxf(hw + hr_s[rbase + j][d], 0.f);
            acc[j][0] = fmaf(hm, w2lo, acc[j][0]);
            acc[j][1] = fmaf(hm, w2hi, acc[j][1]);
        }
    }
    int c0 = cg * 2;
    int wg = wt * 8 + wl;
#pragma unroll
    for (int j = 0; j < 4; ++j) {
        int r = rbase + j;
        size_t base = (size_t)((b * RR + r) * WW + wg) * CC;
        if (c0 < CC)     out_role[base + c0]     = acc[j][0] + b2[c0];
        if (c0 + 1 < CC) out_role[base + c0 + 1] = acc[j][1] + b2[c0 + 1];
    }
}

extern "C" void kernel_launch(void* const* d_in, const int* in_sizes, int n_in,
                              void* d_out, int out_size, void* d_ws, size_t ws_size,
                              hipStream_t stream) {
    const float* hidden  = (const float*)d_in[0];
    const int*   word_ids = (const int*)d_in[1];
    const int*   relpos  = (const int*)d_in[2];
    const float* w_rel   = (const float*)d_in[3];
    const float* b_rel   = (const float*)d_in[4];
    const float* w1      = (const float*)d_in[5];
    const float* b1      = (const float*)d_in[6];
    const float* w2      = (const float*)d_in[7];
    const float* b2      = (const float*)d_in[8];

    float* out0 = (float*)d_out;                    // rel_logits [16*512]
    float* out1 = out0 + BB * SS;                   // role_logits [16*8*256*27]

    int*   first_idx = (int*)d_ws;
    float* h_rel     = (float*)((char*)d_ws + 16384);
    float* h_word    = (float*)((char*)d_ws + 16384 + BB * RR * DD * 4);

    k_first_idx<<<BB, SS, 0, stream>>>(word_ids, first_idx);
    k_rel_logits<<<BB * SS / 4, 256, 0, stream>>>(
        (const float4*)hidden, (const float4*)w_rel, b_rel, out0);
    k_h_rel<<<dim3(DD / 64, BB), 256, 0, stream>>>(hidden, relpos, w1, h_rel);
    k_h_word<<<dim3(DD / 64, BB * WW / 64), 256, 0, stream>>>(hidden, first_idx, w1, h_word);
    k_role<<<dim3(WW / 8, BB), 256, 0, stream>>>(h_word, h_rel, w2, b1, b2, out1);
}

// Round 4
// 84.304 us; speedup vs baseline: 1.9114x; 1.9114x over previous
//
#include <hip/hip_runtime.h>
#include <hip/hip_bf16.h>

#define BB 16
#define SS 512
#define HH 768
#define RR 8
#define DD 512
#define CC 27
#define WW 256

typedef __attribute__((ext_vector_type(8))) short short8;
typedef __attribute__((ext_vector_type(4))) float f32x4;

union PKu { unsigned short us[8]; uint4 u4; short8 s8; };

__device__ __forceinline__ unsigned short f32_to_bf16_rne(float v) {
    unsigned int u = __float_as_uint(v);
    unsigned int r = u + 0x7fffu + ((u >> 16) & 1u);
    return (unsigned short)(r >> 16);
}
__device__ __forceinline__ float bf16_to_f32(unsigned short u) {
    return __uint_as_float(((unsigned int)u) << 16);
}

// ---------------------------------------------------------------------------
// ws layout (bytes):
//   first_idx : int[BB*WW]              @ 0         (16 KB)
//   h_rel     : float[BB*RR*DD]         @ 16384     (256 KB)
//   h_word    : bf16[BB*WW*DD]          @ 278528    (4 MB)
//   w1t       : bf16[DD][2*HH]          @ 4472832   (1.5 MB)   w1t[n][k]=w1[k][n]
//   w2t       : bf16[32][DD]            @ 6045696   (32 KB)    w2t[n][k]=w2[k][n]
// ---------------------------------------------------------------------------

// T1: transpose w1 [1536][512] f32 -> w1t [512][1536] bf16
__global__ __launch_bounds__(256) void k_w1t(const float* __restrict__ w1,
                                             unsigned short* __restrict__ w1t) {
    int kt = blockIdx.x, nt = blockIdx.y, t = threadIdx.x;
    __shared__ unsigned short tile[64][72];
    int i = t >> 2, j4 = (t & 3) * 16;
    const float* src = w1 + (size_t)(kt * 64 + i) * DD + nt * 64 + j4;
#pragma unroll
    for (int v = 0; v < 4; ++v) {
        float4 f = *(const float4*)(src + v * 4);
        tile[i][j4 + v * 4 + 0] = f32_to_bf16_rne(f.x);
        tile[i][j4 + v * 4 + 1] = f32_to_bf16_rne(f.y);
        tile[i][j4 + v * 4 + 2] = f32_to_bf16_rne(f.z);
        tile[i][j4 + v * 4 + 3] = f32_to_bf16_rne(f.w);
    }
    __syncthreads();
    int jj = t >> 2, cb = (t & 3) * 16;
    union { unsigned short us[16]; uint4 u4[2]; } ov;
#pragma unroll
    for (int v = 0; v < 16; ++v) ov.us[v] = tile[cb + v][jj];
    unsigned short* dst = w1t + (size_t)(nt * 64 + jj) * (2 * HH) + kt * 64 + cb;
    *(uint4*)(dst) = ov.u4[0];
    *(uint4*)(dst + 8) = ov.u4[1];
}

// T2: w2 [512][27] f32 -> w2t [32][512] bf16 (cols >= 27 zero)
__global__ __launch_bounds__(256) void k_w2t(const float* __restrict__ w2,
                                             unsigned short* __restrict__ w2t) {
    int t = threadIdx.x;
    for (int idx = t; idx < 32 * DD; idx += 256) {
        int n = idx >> 9, k = idx & (DD - 1);
        float v = (n < CC) ? w2[(size_t)k * CC + n] : 0.f;
        w2t[n * DD + k] = f32_to_bf16_rne(v);
    }
}

// K2: first-occurrence index per (b, word). word_ids sorted along s.
__global__ void k_first_idx(const int* __restrict__ word_ids,
                            int* __restrict__ first_idx) {
    int b = blockIdx.x;
    int t = threadIdx.x;            // 512 threads
    if (t < WW) first_idx[b * WW + t] = -1;
    __syncthreads();
    int wid  = word_ids[b * SS + t];
    int prev = (t == 0) ? -1 : word_ids[b * SS + t - 1];
    if (wid != prev) first_idx[b * WW + wid] = t;   // unique per (b,wid)
}

// K1: rel_logits[b,s] = dot(hidden[b,s,:], w_rel) + b_rel
__global__ __launch_bounds__(256) void k_rel_logits(
    const float4* __restrict__ hid4, const float4* __restrict__ wrel4,
    const float* __restrict__ b_rel, float* __restrict__ out) {
    int t = threadIdx.x;
    int lane = t & 63;
    int row = blockIdx.x * 4 + (t >> 6);     // one wave per row
    int base = row * (HH / 4);               // 192 float4 per row
    float acc = 0.f;
#pragma unroll
    for (int j = 0; j < 3; ++j) {
        float4 v = hid4[base + j * 64 + lane];
        float4 w = wrel4[j * 64 + lane];
        acc += v.x * w.x + v.y * w.y + v.z * w.z + v.w * w.w;
    }
#pragma unroll
    for (int off = 32; off > 0; off >>= 1) acc += __shfl_xor(acc, off, 64);
    if (lane == 0) out[row] = acc + b_rel[0];
}

// K3: h_rel[b,r,d] = sum_h hidden[b, relpos[b,r], h] * w1[HH+h, d]   (f32)
__global__ __launch_bounds__(256) void k_h_rel(
    const float* __restrict__ hidden, const int* __restrict__ relpos,
    const float* __restrict__ w1, float* __restrict__ h_rel) {
    int dc = blockIdx.x;   // 0..7
    int b  = blockIdx.y;   // 0..15
    int t  = threadIdx.x;  // 256
    __shared__ float hid_s[RR][HH];
    for (int idx4 = t; idx4 < RR * (HH / 4); idx4 += 256) {
        int rr = idx4 / (HH / 4);
        int h4 = idx4 % (HH / 4);
        int pos = relpos[b * RR + rr];
        float4 v = ((const float4*)hidden)[(size_t)(b * SS + pos) * (HH / 4) + h4];
        ((float4*)&hid_s[rr][0])[h4] = v;
    }
    __syncthreads();
    int d = dc * 64 + (t & 63);
    int g = t >> 6;
    float acc0 = 0.f, acc1 = 0.f;
    const float* w1b = w1 + (size_t)HH * DD;
#pragma unroll 16
    for (int h = 0; h < HH; ++h) {
        float wv = w1b[(size_t)h * DD + d];
        acc0 = fmaf(hid_s[g][h],     wv, acc0);
        acc1 = fmaf(hid_s[g + 4][h], wv, acc1);
    }
    h_rel[(b * RR + g) * DD + d]     = acc0;
    h_rel[(b * RR + g + 4) * DD + d] = acc1;
}

// K4: h_word = gather(hidden) @ w1[:HH]  via bf16 MFMA. M=4096,N=512,K=768.
// 64x64 tile, 4 waves (2x2), each wave 32x32 = 2x2 frags of 16x16x32.
// LDS rows are 64B = 4 chunks of 16B; swizzle: chunk ^= (row>>1)&3 (2-bit,
// bijective within the row; even bank-quad spread for both b128 write/read).
__global__ __launch_bounds__(256) void k_h_word(
    const float* __restrict__ hidden, const int* __restrict__ first_idx,
    const unsigned short* __restrict__ w1t, unsigned short* __restrict__ h_word) {
    int nt = blockIdx.x;   // 0..7
    int mt = blockIdx.y;   // 0..63
    int t  = threadIdx.x;
    __shared__ __align__(16) unsigned char a_s[4096];  // [64 m][32 k] bf16 swz
    __shared__ __align__(16) unsigned char b_s[4096];  // [64 n][32 k] bf16 swz
    int sm = t >> 2, kq = t & 3;
    int mrow = mt * 64 + sm;
    int bb = mrow >> 8, wd = mrow & 255;
    int src = first_idx[bb * WW + wd];
    const float* arow = (src >= 0) ? hidden + (size_t)(bb * SS + src) * HH : nullptr;
    const unsigned short* brow = w1t + (size_t)(nt * 64 + sm) * (2 * HH);
    unsigned sw_off = sm * 64 + ((unsigned)(kq ^ ((sm >> 1) & 3)) << 4);
    int wv = t >> 6, lane = t & 63;
    int q = lane >> 4, r = lane & 15;
    int wr = wv >> 1, wc = wv & 1;
    unsigned ra[2], rb[2];
#pragma unroll
    for (int i = 0; i < 2; ++i) {
        ra[i] = (wr * 32 + i * 16 + r) * 64 + ((unsigned)(q ^ ((r >> 1) & 3)) << 4);
        rb[i] = (wc * 32 + i * 16 + r) * 64 + ((unsigned)(q ^ ((r >> 1) & 3)) << 4);
    }
    f32x4 acc[2][2];
#pragma unroll
    for (int i = 0; i < 2; ++i)
#pragma unroll
        for (int j = 0; j < 2; ++j) acc[i][j] = (f32x4){0.f, 0.f, 0.f, 0.f};

    for (int kt = 0; kt < HH / 32; ++kt) {
        uint4 aval = {0u, 0u, 0u, 0u};
        if (arow) {
            float4 f0 = *(const float4*)(arow + kt * 32 + kq * 8);
            float4 f1 = *(const float4*)(arow + kt * 32 + kq * 8 + 4);
            PKu pk;
            pk.us[0] = f32_to_bf16_rne(f0.x);
            pk.us[1] = f32_to_bf16_rne(f0.y);
            pk.us[2] = f32_to_bf16_rne(f0.z);
            pk.us[3] = f32_to_bf16_rne(f0.w);
            pk.us[4] = f32_to_bf16_rne(f1.x);
            pk.us[5] = f32_to_bf16_rne(f1.y);
            pk.us[6] = f32_to_bf16_rne(f1.z);
            pk.us[7] = f32_to_bf16_rne(f1.w);
            aval = pk.u4;
        }
        *(uint4*)(a_s + sw_off) = aval;
        *(uint4*)(b_s + sw_off) = *(const uint4*)(brow + kt * 32 + kq * 8);
        __syncthreads();
        short8 af[2], bf2[2];
#pragma unroll
        for (int i = 0; i < 2; ++i) {
            af[i]  = *(const short8*)(a_s + ra[i]);
            bf2[i] = *(const short8*)(b_s + rb[i]);
        }
#pragma unroll
        for (int i = 0; i < 2; ++i)
#pragma unroll
            for (int j = 0; j < 2; ++j)
                acc[i][j] = __builtin_amdgcn_mfma_f32_16x16x32_bf16(
                    af[i], bf2[j], acc[i][j], 0, 0, 0);
        __syncthreads();
    }
#pragma unroll
    for (int i = 0; i < 2; ++i)
#pragma unroll
        for (int j = 0; j < 2; ++j)
#pragma unroll
            for (int reg = 0; reg < 4; ++reg) {
                int mg = mt * 64 + wr * 32 + i * 16 + 4 * q + reg;
                int ng = nt * 64 + wc * 32 + j * 16 + r;
                h_word[(size_t)mg * DD + ng] = f32_to_bf16_rne(acc[i][j][reg]);
            }
}

// K5: role_logits = relu(h_word[b,w,:]+h_rel[b,r,:]+b1) @ w2 + b2 via MFMA.
// block = (b, 16 w): M = 16 words, N = 32 cols, K = 512; r handled by wave x mi.
__global__ __launch_bounds__(256) void k_role(
    const unsigned short* __restrict__ h_word, const float* __restrict__ h_rel,
    const unsigned short* __restrict__ w2t, const float* __restrict__ b1,
    const float* __restrict__ b2, float* __restrict__ out_role) {
    int wt = blockIdx.x;   // 0..15
    int b  = blockIdx.y;   // 0..15
    int t  = threadIdx.x;  // 256
    __shared__ __align__(16) unsigned char hw_s[32768];  // [16 w][512 k] f32 swz (+b1)
    __shared__ float hr_s[RR][DD];                       // 16 KB linear
    __shared__ __align__(16) unsigned char w2_s[32768];  // [32 n][512 k] bf16 swz
    {   // stage hw (+b1), swizzled per 16B chunk (row = 128 chunks, 3-bit XOR ok)
        int wl = t >> 4;
        int cb = (t & 15) * 8;
        const unsigned short* srcr = h_word + (size_t)(b * WW + wt * 16 + wl) * DD;
        unsigned wlx = (wl & 7) << 4;
#pragma unroll
        for (int i = 0; i < 8; ++i) {
            int c = cb + i;
            uint2 hv = *(const uint2*)(srcr + c * 4);
            float4 bv = *(const float4*)(b1 + c * 4);
            float4 o;
            o.x = bf16_to_f32((unsigned short)(hv.x & 0xffffu)) + bv.x;
            o.y = bf16_to_f32((unsigned short)(hv.x >> 16)) + bv.y;
            o.z = bf16_to_f32((unsigned short)(hv.y & 0xffffu)) + bv.z;
            o.w = bf16_to_f32((unsigned short)(hv.y >> 16)) + bv.w;
            *(float4*)(hw_s + wl * 2048 + ((unsigned)(c * 16) ^ wlx)) = o;
        }
    }
#pragma unroll
    for (int idx = t; idx < 1024; idx += 256) {   // stage hr (linear)
        int rr = idx >> 7, c = idx & 127;
        *(float4*)&hr_s[rr][c * 4] =
            *(const float4*)(h_rel + (size_t)(b * RR + rr) * DD + c * 4);
    }
    {   // stage w2t, swizzled (row = 64 chunks, 3-bit XOR ok)
        int n = t >> 3, cb = (t & 7) * 8;
        unsigned nx = (n & 7) << 4;
        const unsigned short* srcw = w2t + n * DD + cb * 8;
#pragma unroll
        for (int i = 0; i < 8; ++i)
            *(uint4*)(w2_s + n * 1024 + ((unsigned)((cb + i) * 16) ^ nx)) =
                *(const uint4*)(srcw + i * 8);
    }
    __syncthreads();
    int wv = t >> 6, lane = t & 63, q = lane >> 4, wl = lane & 15;
    unsigned wlx = (wl & 7) << 4;
    f32x4 acc[2][2];
#pragma unroll
    for (int i = 0; i < 2; ++i)
#pragma unroll
        for (int j = 0; j < 2; ++j) acc[i][j] = (f32x4){0.f, 0.f, 0.f, 0.f};

    for (int ks = 0; ks < DD / 32; ++ks) {
        int k0 = ks * 32;
        short8 bfr[2];
#pragma unroll
        for (int ni = 0; ni < 2; ++ni) {
            int n = ni * 16 + wl;
            bfr[ni] = *(const short8*)(w2_s + n * 1024 +
                        ((unsigned)((4 * ks + q) * 16) ^ wlx));
        }
#pragma unroll
        for (int mi = 0; mi < 2; ++mi) {
            int rr = wv * 2 + mi;
            int c0 = 8 * ks + 2 * q;
            float4 f0 = *(const float4*)(hw_s + wl * 2048 + ((unsigned)(c0 * 16) ^ wlx));
            float4 f1 = *(const float4*)(hw_s + wl * 2048 + ((unsigned)((c0 + 1) * 16) ^ wlx));
            const float* hrp = &hr_s[rr][k0 + 8 * q];
            float4 h0 = *(const float4*)(hrp);
            float4 h1 = *(const float4*)(hrp + 4);
            PKu pk;
            pk.us[0] = f32_to_bf16_rne(fmaxf(f0.x + h0.x, 0.f));
            pk.us[1] = f32_to_bf16_rne(fmaxf(f0.y + h0.y, 0.f));
            pk.us[2] = f32_to_bf16_rne(fmaxf(f0.z + h0.z, 0.f));
            pk.us[3] = f32_to_bf16_rne(fmaxf(f0.w + h0.w, 0.f));
            pk.us[4] = f32_to_bf16_rne(fmaxf(f1.x + h1.x, 0.f));
            pk.us[5] = f32_to_bf16_rne(fmaxf(f1.y + h1.y, 0.f));
            pk.us[6] = f32_to_bf16_rne(fmaxf(f1.z + h1.z, 0.f));
            pk.us[7] = f32_to_bf16_rne(fmaxf(f1.w + h1.w, 0.f));
#pragma unroll
            for (int ni = 0; ni < 2; ++ni)
                acc[mi][ni] = __builtin_amdgcn_mfma_f32_16x16x32_bf16(
                    pk.s8, bfr[ni], acc[mi][ni], 0, 0, 0);
        }
    }
#pragma unroll
    for (int mi = 0; mi < 2; ++mi) {
        int rr = wv * 2 + mi;
#pragma unroll
        for (int ni = 0; ni < 2; ++ni) {
            int c = ni * 16 + wl;
            if (c < CC) {
#pragma unroll
                for (int reg = 0; reg < 4; ++reg) {
                    int wg = wt * 16 + 4 * q + reg;
                    out_role[(size_t)((b * RR + rr) * WW + wg) * CC + c] =
                        acc[mi][ni][reg] + b2[c];
                }
            }
        }
    }
}

extern "C" void kernel_launch(void* const* d_in, const int* in_sizes, int n_in,
                              void* d_out, int out_size, void* d_ws, size_t ws_size,
                              hipStream_t stream) {
    const float* hidden   = (const float*)d_in[0];
    const int*   word_ids = (const int*)d_in[1];
    const int*   relpos   = (const int*)d_in[2];
    const float* w_rel    = (const float*)d_in[3];
    const float* b_rel    = (const float*)d_in[4];
    const float* w1       = (const float*)d_in[5];
    const float* b1       = (const float*)d_in[6];
    const float* w2       = (const float*)d_in[7];
    const float* b2       = (const float*)d_in[8];

    float* out0 = (float*)d_out;                    // rel_logits [16*512]
    float* out1 = out0 + BB * SS;                   // role_logits [16*8*256*27]

    int*            first_idx = (int*)d_ws;
    float*          h_rel  = (float*)((char*)d_ws + 16384);
    unsigned short* h_word = (unsigned short*)((char*)d_ws + 278528);
    unsigned short* w1t    = (unsigned short*)((char*)d_ws + 4472832);
    unsigned short* w2t    = (unsigned short*)((char*)d_ws + 6045696);

    k_w1t<<<dim3(2 * HH / 64, DD / 64), 256, 0, stream>>>(w1, w1t);
    k_w2t<<<1, 256, 0, stream>>>(w2, w2t);
    k_first_idx<<<BB, SS, 0, stream>>>(word_ids, first_idx);
    k_rel_logits<<<BB * SS / 4, 256, 0, stream>>>(
        (const float4*)hidden, (const float4*)w_rel, b_rel, out0);
    k_h_rel<<<dim3(DD / 64, BB), 256, 0, stream>>>(hidden, relpos, w1, h_rel);
    k_h_word<<<dim3(DD / 64, BB * WW / 64), 256, 0, stream>>>(
        hidden, first_idx, w1t, h_word);
    k_role<<<dim3(WW / 16, BB), 256, 0, stream>>>(h_word, h_rel, w2t, b1, b2, out1);
}

// Round 5
// 57.304 us; speedup vs baseline: 2.8120x; 1.4712x over previous
//
#include <hip/hip_runtime.h>
#include <hip/hip_bf16.h>

#define BB 16
#define SS 512
#define HH 768
#define RR 8
#define DD 512
#define CC 27
#define WW 256

typedef __attribute__((ext_vector_type(8))) short short8;
typedef __attribute__((ext_vector_type(4))) float f32x4;

union PKu { unsigned short us[8]; uint4 u4; short8 s8; };

__device__ __forceinline__ unsigned short f32_to_bf16_rne(float v) {
    unsigned int u = __float_as_uint(v);
    unsigned int r = u + 0x7fffu + ((u >> 16) & 1u);
    return (unsigned short)(r >> 16);
}
__device__ __forceinline__ float bf16_to_f32(unsigned short u) {
    return __uint_as_float(((unsigned int)u) << 16);
}

__device__ __forceinline__ void glds16(const void* g, void* l) {
    __builtin_amdgcn_global_load_lds(
        (const __attribute__((address_space(1))) unsigned int*)g,
        (__attribute__((address_space(3))) unsigned int*)l, 16, 0, 0);
}

// ---------------------------------------------------------------------------
// ws layout (bytes):
//   first_hidden : bf16[BB*WW][HH]   @ 0          (6291456)  dense, zero rows for absent words
//   rel_hidden   : bf16[BB*RR][HH]   @ 6291456    (196608)
//   w1t          : bf16[DD][2*HH]    @ 6488064    (1572864)  w1t[n][k]=w1[k][n]
//   w2t          : bf16[32][DD]      @ 8060928    (32768)
//   h_word       : bf16[BB*WW][DD]   @ 8093696    (4194304)
//   h_rel        : bf16[BB*RR][DD]   @ 12288000   (131072)
// ---------------------------------------------------------------------------

// K_A: block 0..191 -> w1t transpose; 192 -> w2t; 193..208 -> per-b zero + rel gather
__global__ __launch_bounds__(256) void k_prep(
    const float* __restrict__ w1, const float* __restrict__ w2,
    const int* __restrict__ word_ids, const int* __restrict__ relpos,
    const float* __restrict__ hidden,
    unsigned short* __restrict__ w1t, unsigned short* __restrict__ w2t,
    unsigned short* __restrict__ first_hidden,
    unsigned short* __restrict__ rel_hidden) {
    __shared__ unsigned short tile[64][72];
    __shared__ int pres[WW];
    int x = blockIdx.x, t = threadIdx.x;
    if (x < 192) {              // w1 [1536][512] f32 -> w1t [512][1536] bf16
        int kt = x >> 3, nt = x & 7;
        int i = t >> 2, j4 = (t & 3) * 16;
        const float* src = w1 + (size_t)(kt * 64 + i) * DD + nt * 64 + j4;
#pragma unroll
        for (int v = 0; v < 4; ++v) {
            float4 f = *(const float4*)(src + v * 4);
            tile[i][j4 + v * 4 + 0] = f32_to_bf16_rne(f.x);
            tile[i][j4 + v * 4 + 1] = f32_to_bf16_rne(f.y);
            tile[i][j4 + v * 4 + 2] = f32_to_bf16_rne(f.z);
            tile[i][j4 + v * 4 + 3] = f32_to_bf16_rne(f.w);
        }
        __syncthreads();
        int jj = t >> 2, cb = (t & 3) * 16;
        union { unsigned short us[16]; uint4 u4[2]; } ov;
#pragma unroll
        for (int v = 0; v < 16; ++v) ov.us[v] = tile[cb + v][jj];
        unsigned short* dst = w1t + (size_t)(nt * 64 + jj) * (2 * HH) + kt * 64 + cb;
        *(uint4*)(dst) = ov.u4[0];
        *(uint4*)(dst + 8) = ov.u4[1];
    } else if (x == 192) {      // w2 [512][27] -> w2t [32][512] bf16
        for (int idx = t; idx < 32 * DD; idx += 256) {
            int n = idx >> 9, k = idx & (DD - 1);
            float v = (n < CC) ? w2[(size_t)k * CC + n] : 0.f;
            w2t[n * DD + k] = f32_to_bf16_rne(v);
        }
    } else {                    // per-batch: zero absent rows + rel gather
        int b = x - 193;
        pres[t] = 0;
        __syncthreads();
        for (int s = t; s < SS; s += 256) pres[word_ids[b * SS + s]] = 1;
        __syncthreads();
        if (!pres[t]) {         // thread t owns word t
            uint4 z = {0u, 0u, 0u, 0u};
            unsigned short* dst = first_hidden + (size_t)(b * WW + t) * HH;
#pragma unroll 4
            for (int c = 0; c < 96; ++c) *(uint4*)(dst + c * 8) = z;
        }
        for (int idx = t; idx < 1024; idx += 256) {  // 8 rel rows x 96 chunks
            int rr = idx >> 7, c = idx & 127;
            if (c < 96) {
                int pos = relpos[b * RR + rr];
                const float* srow = hidden + (size_t)(b * SS + pos) * HH + c * 8;
                PKu pk;
#pragma unroll
                for (int e = 0; e < 8; ++e) pk.us[e] = f32_to_bf16_rne(srow[e]);
                *(uint4*)(rel_hidden + (size_t)(b * RR + rr) * HH + c * 8) = pk.u4;
            }
        }
    }
}

// K_B: rel_logits + first-occurrence bf16 row scatter. One wave per (b,s) row.
__global__ __launch_bounds__(256) void k_rel_gather(
    const float* __restrict__ hidden, const int* __restrict__ word_ids,
    const float4* __restrict__ wrel4, const float* __restrict__ b_rel,
    float* __restrict__ out0, unsigned short* __restrict__ first_hidden) {
    int t = threadIdx.x, lane = t & 63;
    int row = blockIdx.x * 4 + (t >> 6);     // b*512+s
    const float4* hid4 = (const float4*)hidden + (size_t)row * (HH / 4);
    float4 v[3];
    float acc = 0.f;
#pragma unroll
    for (int j = 0; j < 3; ++j) {
        v[j] = hid4[j * 64 + lane];
        float4 w = wrel4[j * 64 + lane];
        acc += v[j].x * w.x + v[j].y * w.y + v[j].z * w.z + v[j].w * w.w;
    }
#pragma unroll
    for (int off = 32; off > 0; off >>= 1) acc += __shfl_xor(acc, off, 64);
    if (lane == 0) out0[row] = acc + b_rel[0];
    int wid = word_ids[row];
    int s = row & (SS - 1);
    int prev = (s == 0) ? -1 : word_ids[row - 1];
    if (wid != prev) {                       // first occurrence (wave-uniform)
        int b = row >> 9;
        unsigned short* dst = first_hidden + (size_t)(b * WW + wid) * HH;
#pragma unroll
        for (int j = 0; j < 3; ++j) {
            union { unsigned short us[4]; uint2 u2; } pk;
            pk.us[0] = f32_to_bf16_rne(v[j].x);
            pk.us[1] = f32_to_bf16_rne(v[j].y);
            pk.us[2] = f32_to_bf16_rne(v[j].z);
            pk.us[3] = f32_to_bf16_rne(v[j].w);
            *(uint2*)(dst + j * 256 + lane * 4) = pk.u2;
        }
    }
}

// K_C: C[M][512] = A[M][768] @ w1t[:, kbase:kbase+768]^T   (all bf16, MFMA)
// 128x64 tile, BK=64, 4 waves 2x2, per wave 64x32 (4x2 frags of 16x16x32).
// global_load_lds w=16 with XOR-swizzled source; swizzled ds_read (conflict-free).
__global__ __launch_bounds__(256) void k_gemm(
    const unsigned short* __restrict__ A, const unsigned short* __restrict__ Bt,
    unsigned short* __restrict__ C, int kbase) {
    __shared__ __align__(16) unsigned char a_s[16384];  // [128 m][8 chunks of 16B]
    __shared__ __align__(16) unsigned char b_s[8192];   // [64 n][8 chunks]
    int nt = blockIdx.x;   // N/64
    int mt = blockIdx.y;   // M/128
    int t = threadIdx.x;
    int wv = t >> 6, lane = t & 63;
    int wr = wv >> 1, wc = wv & 1;
    int q = lane >> 4, r = lane & 15;
    int lrow8 = lane >> 3, lchunk = lane & 7;

    const unsigned char* aPg[4];
    unsigned a_lds[4];
#pragma unroll
    for (int i = 0; i < 4; ++i) {
        int seg = wv * 4 + i;
        int row = seg * 8 + lrow8;                   // 0..127
        int sc = lchunk ^ (row & 7);                 // inverse-swizzled source chunk
        aPg[i] = (const unsigned char*)A + (size_t)(mt * 128 + row) * (HH * 2) + sc * 16;
        a_lds[i] = seg * 1024 + (lane << 4);
    }
    const unsigned char* bPg[2];
    unsigned b_lds[2];
#pragma unroll
    for (int j = 0; j < 2; ++j) {
        int seg = wv * 2 + j;
        int row = seg * 8 + lrow8;                   // 0..63
        int sc = lchunk ^ (row & 7);
        bPg[j] = (const unsigned char*)Bt + (size_t)(nt * 64 + row) * (2 * HH * 2)
                 + (size_t)kbase * 2 + sc * 16;
        b_lds[j] = seg * 1024 + (lane << 4);
    }
    int arow[4], brow[2];
#pragma unroll
    for (int mi = 0; mi < 4; ++mi) arow[mi] = wr * 64 + mi * 16 + r;
#pragma unroll
    for (int ni = 0; ni < 2; ++ni) brow[ni] = wc * 32 + ni * 16 + r;

    f32x4 acc[4][2];
#pragma unroll
    for (int mi = 0; mi < 4; ++mi)
#pragma unroll
        for (int ni = 0; ni < 2; ++ni) acc[mi][ni] = (f32x4){0.f, 0.f, 0.f, 0.f};

    for (int kt = 0; kt < HH / 64; ++kt) {
#pragma unroll
        for (int i = 0; i < 4; ++i) glds16(aPg[i] + kt * 128, a_s + a_lds[i]);
#pragma unroll
        for (int j = 0; j < 2; ++j) glds16(bPg[j] + kt * 128, b_s + b_lds[j]);
        __syncthreads();   // drains vmcnt(0): staged data visible
#pragma unroll
        for (int ks = 0; ks < 2; ++ks) {
            int c = ks * 4 + q;
            short8 bfr[2];
#pragma unroll
            for (int ni = 0; ni < 2; ++ni)
                bfr[ni] = *(const short8*)(b_s + brow[ni] * 128 +
                            ((c ^ (brow[ni] & 7)) << 4));
#pragma unroll
            for (int mi = 0; mi < 4; ++mi) {
                short8 af = *(const short8*)(a_s + arow[mi] * 128 +
                            ((c ^ (arow[mi] & 7)) << 4));
                acc[mi][0] = __builtin_amdgcn_mfma_f32_16x16x32_bf16(
                    af, bfr[0], acc[mi][0], 0, 0, 0);
                acc[mi][1] = __builtin_amdgcn_mfma_f32_16x16x32_bf16(
                    af, bfr[1], acc[mi][1], 0, 0, 0);
            }
        }
        __syncthreads();   // all reads done before next-tile glds lands
    }
#pragma unroll
    for (int mi = 0; mi < 4; ++mi) {
        int m = mt * 128 + wr * 64 + mi * 16 + q * 4;
#pragma unroll
        for (int ni = 0; ni < 2; ++ni) {
            int n = nt * 64 + wc * 32 + ni * 16 + r;
#pragma unroll
            for (int reg = 0; reg < 4; ++reg)
                C[(size_t)(m + reg) * DD + n] = f32_to_bf16_rne(acc[mi][ni][reg]);
        }
    }
}

// K_E: role_logits = relu(h_word[b,w,:]+h_rel[b,r,:]+b1) @ w2 + b2 via MFMA.
__global__ __launch_bounds__(256) void k_role(
    const unsigned short* __restrict__ h_word, const unsigned short* __restrict__ h_rel,
    const unsigned short* __restrict__ w2t, const float* __restrict__ b1,
    const float* __restrict__ b2, float* __restrict__ out_role) {
    int wt = blockIdx.x;   // 0..15
    int b  = blockIdx.y;   // 0..15
    int t  = threadIdx.x;  // 256
    __shared__ __align__(16) unsigned char hw_s[32768];  // [16 w][512 k] f32 swz (+b1)
    __shared__ float hr_s[RR][DD];                       // 16 KB linear
    __shared__ __align__(16) unsigned char w2_s[32768];  // [32 n][512 k] bf16 swz
    {   // stage hw (+b1), swizzled per 16B chunk
        int wl = t >> 4;
        int cb = (t & 15) * 8;
        const unsigned short* srcr = h_word + (size_t)(b * WW + wt * 16 + wl) * DD;
        unsigned wlx = (wl & 7) << 4;
#pragma unroll
        for (int i = 0; i < 8; ++i) {
            int c = cb + i;
            uint2 hv = *(const uint2*)(srcr + c * 4);
            float4 bv = *(const float4*)(b1 + c * 4);
            float4 o;
            o.x = bf16_to_f32((unsigned short)(hv.x & 0xffffu)) + bv.x;
            o.y = bf16_to_f32((unsigned short)(hv.x >> 16)) + bv.y;
            o.z = bf16_to_f32((unsigned short)(hv.y & 0xffffu)) + bv.z;
            o.w = bf16_to_f32((unsigned short)(hv.y >> 16)) + bv.w;
            *(float4*)(hw_s + wl * 2048 + ((unsigned)(c * 16) ^ wlx)) = o;
        }
    }
    for (int idx = t; idx < 512; idx += 256) {   // stage hr bf16 -> f32 linear
        int rr = idx >> 6, cc = (idx & 63) * 8;
        PKu hv;
        hv.u4 = *(const uint4*)(h_rel + (size_t)(b * RR + rr) * DD + cc);
        float4 o0, o1;
        o0.x = bf16_to_f32(hv.us[0]); o0.y = bf16_to_f32(hv.us[1]);
        o0.z = bf16_to_f32(hv.us[2]); o0.w = bf16_to_f32(hv.us[3]);
        o1.x = bf16_to_f32(hv.us[4]); o1.y = bf16_to_f32(hv.us[5]);
        o1.z = bf16_to_f32(hv.us[6]); o1.w = bf16_to_f32(hv.us[7]);
        *(float4*)&hr_s[rr][cc]     = o0;
        *(float4*)&hr_s[rr][cc + 4] = o1;
    }
    {   // stage w2t, swizzled
        int n = t >> 3, cb = (t & 7) * 8;
        unsigned nx = (n & 7) << 4;
        const unsigned short* srcw = w2t + n * DD + cb * 8;
#pragma unroll
        for (int i = 0; i < 8; ++i)
            *(uint4*)(w2_s + n * 1024 + ((unsigned)((cb + i) * 16) ^ nx)) =
                *(const uint4*)(srcw + i * 8);
    }
    __syncthreads();
    int wv = t >> 6, lane = t & 63, q = lane >> 4, wl = lane & 15;
    unsigned wlx = (wl & 7) << 4;
    f32x4 acc[2][2];
#pragma unroll
    for (int i = 0; i < 2; ++i)
#pragma unroll
        for (int j = 0; j < 2; ++j) acc[i][j] = (f32x4){0.f, 0.f, 0.f, 0.f};

    for (int ks = 0; ks < DD / 32; ++ks) {
        int k0 = ks * 32;
        short8 bfr[2];
#pragma unroll
        for (int ni = 0; ni < 2; ++ni) {
            int n = ni * 16 + wl;
            bfr[ni] = *(const short8*)(w2_s + n * 1024 +
                        ((unsigned)((4 * ks + q) * 16) ^ wlx));
        }
#pragma unroll
        for (int mi = 0; mi < 2; ++mi) {
            int rr = wv * 2 + mi;
            int c0 = 8 * ks + 2 * q;
            float4 f0 = *(const float4*)(hw_s + wl * 2048 + ((unsigned)(c0 * 16) ^ wlx));
            float4 f1 = *(const float4*)(hw_s + wl * 2048 + ((unsigned)((c0 + 1) * 16) ^ wlx));
            const float* hrp = &hr_s[rr][k0 + 8 * q];
            float4 h0 = *(const float4*)(hrp);
            float4 h1 = *(const float4*)(hrp + 4);
            PKu pk;
            pk.us[0] = f32_to_bf16_rne(fmaxf(f0.x + h0.x, 0.f));
            pk.us[1] = f32_to_bf16_rne(fmaxf(f0.y + h0.y, 0.f));
            pk.us[2] = f32_to_bf16_rne(fmaxf(f0.z + h0.z, 0.f));
            pk.us[3] = f32_to_bf16_rne(fmaxf(f0.w + h0.w, 0.f));
            pk.us[4] = f32_to_bf16_rne(fmaxf(f1.x + h1.x, 0.f));
            pk.us[5] = f32_to_bf16_rne(fmaxf(f1.y + h1.y, 0.f));
            pk.us[6] = f32_to_bf16_rne(fmaxf(f1.z + h1.z, 0.f));
            pk.us[7] = f32_to_bf16_rne(fmaxf(f1.w + h1.w, 0.f));
#pragma unroll
            for (int ni = 0; ni < 2; ++ni)
                acc[mi][ni] = __builtin_amdgcn_mfma_f32_16x16x32_bf16(
                    pk.s8, bfr[ni], acc[mi][ni], 0, 0, 0);
        }
    }
#pragma unroll
    for (int mi = 0; mi < 2; ++mi) {
        int rr = wv * 2 + mi;
#pragma unroll
        for (int ni = 0; ni < 2; ++ni) {
            int c = ni * 16 + wl;
            if (c < CC) {
#pragma unroll
                for (int reg = 0; reg < 4; ++reg) {
                    int wg = wt * 16 + 4 * q + reg;
                    out_role[(size_t)((b * RR + rr) * WW + wg) * CC + c] =
                        acc[mi][ni][reg] + b2[c];
                }
            }
        }
    }
}

extern "C" void kernel_launch(void* const* d_in, const int* in_sizes, int n_in,
                              void* d_out, int out_size, void* d_ws, size_t ws_size,
                              hipStream_t stream) {
    const float* hidden   = (const float*)d_in[0];
    const int*   word_ids = (const int*)d_in[1];
    const int*   relpos   = (const int*)d_in[2];
    const float* w_rel    = (const float*)d_in[3];
    const float* b_rel    = (const float*)d_in[4];
    const float* w1       = (const float*)d_in[5];
    const float* b1       = (const float*)d_in[6];
    const float* w2       = (const float*)d_in[7];
    const float* b2       = (const float*)d_in[8];

    float* out0 = (float*)d_out;                    // rel_logits [16*512]
    float* out1 = out0 + BB * SS;                   // role_logits [16*8*256*27]

    unsigned short* first_hidden = (unsigned short*)d_ws;
    unsigned short* rel_hidden   = (unsigned short*)((char*)d_ws + 6291456);
    unsigned short* w1t          = (unsigned short*)((char*)d_ws + 6488064);
    unsigned short* w2t          = (unsigned short*)((char*)d_ws + 8060928);
    unsigned short* h_word       = (unsigned short*)((char*)d_ws + 8093696);
    unsigned short* h_rel        = (unsigned short*)((char*)d_ws + 12288000);

    k_prep<<<209, 256, 0, stream>>>(w1, w2, word_ids, relpos, hidden,
                                    w1t, w2t, first_hidden, rel_hidden);
    k_rel_gather<<<BB * SS / 4, 256, 0, stream>>>(
        hidden, word_ids, (const float4*)w_rel, b_rel, out0, first_hidden);
    k_gemm<<<dim3(DD / 64, BB * WW / 128), 256, 0, stream>>>(
        first_hidden, w1t, h_word, 0);
    k_gemm<<<dim3(DD / 64, 1), 256, 0, stream>>>(
        rel_hidden, w1t, h_rel, HH);
    k_role<<<dim3(WW / 16, BB), 256, 0, stream>>>(h_word, h_rel, w2t, b1, b2, out1);
}

// Round 6
// 46.524 us; speedup vs baseline: 3.4636x; 1.2317x over previous
//
#include <hip/hip_runtime.h>
#include <hip/hip_bf16.h>

#define BB 16
#define SS 512
#define HH 768
#define RR 8
#define DD 512
#define CC 27
#define WW 256

typedef __attribute__((ext_vector_type(8))) short short8;
typedef __attribute__((ext_vector_type(4))) float f32x4;

union PKu { unsigned short us[8]; uint4 u4; short8 s8; };

__device__ __forceinline__ unsigned short f32_to_bf16_rne(float v) {
    unsigned int u = __float_as_uint(v);
    unsigned int r = u + 0x7fffu + ((u >> 16) & 1u);
    return (unsigned short)(r >> 16);
}
__device__ __forceinline__ float bf16_to_f32(unsigned short u) {
    return __uint_as_float(((unsigned int)u) << 16);
}

__device__ __forceinline__ void glds16(const void* g, void* l) {
    __builtin_amdgcn_global_load_lds(
        (const __attribute__((address_space(1))) unsigned int*)g,
        (__attribute__((address_space(3))) unsigned int*)l, 16, 0, 0);
}

// ---------------------------------------------------------------------------
// ws layout (bytes):
//   first_hidden : bf16[BB*WW][HH]   @ 0          (6291456)
//   rel_hidden   : bf16[BB*RR][HH]   @ 6291456    (196608)
//   w1t          : bf16[DD][2*HH]    @ 6488064    (1572864)
//   w2t          : bf16[32][DD]      @ 8060928    (32768)
//   h_word       : bf16[BB*WW][DD]   @ 8093696    (4194304)
//   h_rel        : bf16[BB*RR][DD]   @ 12288000   (131072)
// ---------------------------------------------------------------------------

// K1: blocks 0..2047: rel_logits + first-occurrence scatter (1 wave per row)
//     blocks 2048..2256: w1t transpose / w2t / per-b zero + rel gather
__global__ __launch_bounds__(256) void k_front(
    const float* __restrict__ hidden, const int* __restrict__ word_ids,
    const int* __restrict__ relpos, const float4* __restrict__ wrel4,
    const float* __restrict__ b_rel, const float* __restrict__ w1,
    const float* __restrict__ w2, float* __restrict__ out0,
    unsigned short* __restrict__ first_hidden,
    unsigned short* __restrict__ rel_hidden,
    unsigned short* __restrict__ w1t, unsigned short* __restrict__ w2t) {
    int bid = blockIdx.x, t = threadIdx.x;
    if (bid < 2048) {
        int lane = t & 63;
        int row = bid * 4 + (t >> 6);            // b*512+s
        const float4* hid4 = (const float4*)hidden + (size_t)row * (HH / 4);
        float4 v[3];
        float acc = 0.f;
#pragma unroll
        for (int j = 0; j < 3; ++j) {
            v[j] = hid4[j * 64 + lane];
            float4 w = wrel4[j * 64 + lane];
            acc += v[j].x * w.x + v[j].y * w.y + v[j].z * w.z + v[j].w * w.w;
        }
#pragma unroll
        for (int off = 32; off > 0; off >>= 1) acc += __shfl_xor(acc, off, 64);
        if (lane == 0) out0[row] = acc + b_rel[0];
        int wid = word_ids[row];
        int s = row & (SS - 1);
        int prev = (s == 0) ? -1 : word_ids[row - 1];
        if (wid != prev) {                       // first occurrence (wave-uniform)
            int b = row >> 9;
            unsigned short* dst = first_hidden + (size_t)(b * WW + wid) * HH;
#pragma unroll
            for (int j = 0; j < 3; ++j) {
                union { unsigned short us[4]; uint2 u2; } pk;
                pk.us[0] = f32_to_bf16_rne(v[j].x);
                pk.us[1] = f32_to_bf16_rne(v[j].y);
                pk.us[2] = f32_to_bf16_rne(v[j].z);
                pk.us[3] = f32_to_bf16_rne(v[j].w);
                *(uint2*)(dst + j * 256 + lane * 4) = pk.u2;
            }
        }
        return;
    }
    int x = bid - 2048;
    if (x < 192) {              // w1 [1536][512] f32 -> w1t [512][1536] bf16
        __shared__ unsigned short tile[64][72];
        int kt = x >> 3, nt = x & 7;
        int i = t >> 2, j4 = (t & 3) * 16;
        const float* src = w1 + (size_t)(kt * 64 + i) * DD + nt * 64 + j4;
#pragma unroll
        for (int v = 0; v < 4; ++v) {
            float4 f = *(const float4*)(src + v * 4);
            tile[i][j4 + v * 4 + 0] = f32_to_bf16_rne(f.x);
            tile[i][j4 + v * 4 + 1] = f32_to_bf16_rne(f.y);
            tile[i][j4 + v * 4 + 2] = f32_to_bf16_rne(f.z);
            tile[i][j4 + v * 4 + 3] = f32_to_bf16_rne(f.w);
        }
        __syncthreads();
        int jj = t >> 2, cb = (t & 3) * 16;
        union { unsigned short us[16]; uint4 u4[2]; } ov;
#pragma unroll
        for (int v = 0; v < 16; ++v) ov.us[v] = tile[cb + v][jj];
        unsigned short* dst = w1t + (size_t)(nt * 64 + jj) * (2 * HH) + kt * 64 + cb;
        *(uint4*)(dst) = ov.u4[0];
        *(uint4*)(dst + 8) = ov.u4[1];
    } else if (x == 192) {      // w2 [512][27] -> w2t [32][512] bf16
        for (int idx = t; idx < 32 * DD; idx += 256) {
            int n = idx >> 9, k = idx & (DD - 1);
            float v = (n < CC) ? w2[(size_t)k * CC + n] : 0.f;
            w2t[n * DD + k] = f32_to_bf16_rne(v);
        }
    } else {                    // per-batch: zero absent rows + rel gather
        __shared__ int pres[WW];
        int b = x - 193;
        pres[t] = 0;
        __syncthreads();
        for (int s = t; s < SS; s += 256) pres[word_ids[b * SS + s]] = 1;
        __syncthreads();
        if (!pres[t]) {         // thread t owns word t
            uint4 z = {0u, 0u, 0u, 0u};
            unsigned short* dst = first_hidden + (size_t)(b * WW + t) * HH;
#pragma unroll 4
            for (int c = 0; c < 96; ++c) *(uint4*)(dst + c * 8) = z;
        }
        for (int idx = t; idx < 1024; idx += 256) {  // 8 rel rows x 96 chunks
            int rr = idx >> 7, c = idx & 127;
            if (c < 96) {
                int pos = relpos[b * RR + rr];
                const float* srow = hidden + (size_t)(b * SS + pos) * HH + c * 8;
                PKu pk;
#pragma unroll
                for (int e = 0; e < 8; ++e) pk.us[e] = f32_to_bf16_rne(srow[e]);
                *(uint4*)(rel_hidden + (size_t)(b * RR + rr) * HH + c * 8) = pk.u4;
            }
        }
    }
}

// K2: C = A @ w1t[:, kbase:kbase+768]^T, all bf16 MFMA.
// 64x64 tile, BK=128, double-buffered LDS (2x32KB), prefetch-then-compute,
// 4 waves 2x2, per wave 32x32. grid (8, 66): mt<64 -> h_word; else h_rel.
__global__ __launch_bounds__(256) void k_gemm(
    const unsigned short* __restrict__ first_hidden,
    const unsigned short* __restrict__ rel_hidden,
    const unsigned short* __restrict__ w1t,
    unsigned short* __restrict__ h_word, unsigned short* __restrict__ h_rel) {
    __shared__ __align__(16) unsigned char a_s[32768];  // 2 x [64 rows][256B]
    __shared__ __align__(16) unsigned char b_s[32768];
    int nt = blockIdx.x;   // 0..7
    int mt = blockIdx.y;   // 0..65
    const unsigned short* A;
    unsigned short* C;
    int kbase, m0;
    if (mt < 64) { A = first_hidden; C = h_word; kbase = 0;  m0 = mt * 64; }
    else         { A = rel_hidden;   C = h_rel;  kbase = HH; m0 = (mt - 64) * 64; }
    int t = threadIdx.x;
    int wv = t >> 6, lane = t & 63;
    int wr = wv >> 1, wc = wv & 1;
    int q = lane >> 4, r = lane & 15;

    const unsigned char* aP[4];
    const unsigned char* bP[4];
    unsigned lofs[4];
#pragma unroll
    for (int j = 0; j < 4; ++j) {
        int ci = j * 256 + t;                    // 0..1023
        int row = ci >> 4, ch = ci & 15;
        int sc = ch ^ (row & 7);                 // inverse-swizzled source chunk
        aP[j] = (const unsigned char*)A + (size_t)(m0 + row) * (HH * 2) + sc * 16;
        bP[j] = (const unsigned char*)w1t + (size_t)(nt * 64 + row) * (2 * HH * 2)
                + (size_t)kbase * 2 + sc * 16;
        lofs[j] = ci * 16;
    }
    f32x4 acc[2][2];
#pragma unroll
    for (int mi = 0; mi < 2; ++mi)
#pragma unroll
        for (int ni = 0; ni < 2; ++ni) acc[mi][ni] = (f32x4){0.f, 0.f, 0.f, 0.f};

    // prologue: stage kt=0 into buf 0
#pragma unroll
    for (int j = 0; j < 4; ++j) glds16(aP[j], a_s + lofs[j]);
#pragma unroll
    for (int j = 0; j < 4; ++j) glds16(bP[j], b_s + lofs[j]);
    __syncthreads();

#pragma unroll
    for (int kt = 0; kt < 6; ++kt) {
        if (kt < 5) {          // prefetch kt+1 into other buffer (overlaps compute)
            unsigned nb = ((kt + 1) & 1) * 16384;
#pragma unroll
            for (int j = 0; j < 4; ++j) glds16(aP[j] + (kt + 1) * 256, a_s + nb + lofs[j]);
#pragma unroll
            for (int j = 0; j < 4; ++j) glds16(bP[j] + (kt + 1) * 256, b_s + nb + lofs[j]);
        }
        unsigned bo = (kt & 1) * 16384;
#pragma unroll
        for (int ks = 0; ks < 4; ++ks) {
            int c = ks * 4 + q;
            short8 bfr[2];
#pragma unroll
            for (int ni = 0; ni < 2; ++ni) {
                int row = wc * 32 + ni * 16 + r;
                bfr[ni] = *(const short8*)(b_s + bo + row * 256 + ((c ^ (row & 7)) << 4));
            }
#pragma unroll
            for (int mi = 0; mi < 2; ++mi) {
                int row = wr * 32 + mi * 16 + r;
                short8 af = *(const short8*)(a_s + bo + row * 256 + ((c ^ (row & 7)) << 4));
                acc[mi][0] = __builtin_amdgcn_mfma_f32_16x16x32_bf16(
                    af, bfr[0], acc[mi][0], 0, 0, 0);
                acc[mi][1] = __builtin_amdgcn_mfma_f32_16x16x32_bf16(
                    af, bfr[1], acc[mi][1], 0, 0, 0);
            }
        }
        __syncthreads();   // drains prefetch vmcnt + protects buffer reuse
    }
#pragma unroll
    for (int mi = 0; mi < 2; ++mi) {
        int m = m0 + wr * 32 + mi * 16 + q * 4;
#pragma unroll
        for (int ni = 0; ni < 2; ++ni) {
            int n = nt * 64 + wc * 32 + ni * 16 + r;
#pragma unroll
            for (int reg = 0; reg < 4; ++reg)
                C[(size_t)(m + reg) * DD + n] = f32_to_bf16_rne(acc[mi][ni][reg]);
        }
    }
}

// K3: role_logits = relu(h_word[b,w,:]+h_rel[b,r,:]+b1) @ w2 + b2 via MFMA.
// 512 threads = 8 waves, one r per wave (2 waves/SIMD -> MFMA||VALU overlap).
__global__ __launch_bounds__(512) void k_role(
    const unsigned short* __restrict__ h_word, const unsigned short* __restrict__ h_rel,
    const unsigned short* __restrict__ w2t, const float* __restrict__ b1,
    const float* __restrict__ b2, float* __restrict__ out_role) {
    int wt = blockIdx.x;   // 0..15
    int b  = blockIdx.y;   // 0..15
    int t  = threadIdx.x;  // 512
    __shared__ __align__(16) unsigned char hw_s[32768];  // [16 w][512 k] f32 swz (+b1)
    __shared__ float hr_s[RR][DD];                       // 16 KB linear
    __shared__ __align__(16) unsigned char w2_s[32768];  // [32 n][512 k] bf16 swz
    {   // stage hw (+b1), swizzled per 16B chunk
        int wl = t >> 5;
        int cb = (t & 31) * 4;
        const unsigned short* srcr = h_word + (size_t)(b * WW + wt * 16 + wl) * DD;
        unsigned wlx = (wl & 7) << 4;
#pragma unroll
        for (int i = 0; i < 4; ++i) {
            int c = cb + i;
            uint2 hv = *(const uint2*)(srcr + c * 4);
            float4 bv = *(const float4*)(b1 + c * 4);
            float4 o;
            o.x = bf16_to_f32((unsigned short)(hv.x & 0xffffu)) + bv.x;
            o.y = bf16_to_f32((unsigned short)(hv.x >> 16)) + bv.y;
            o.z = bf16_to_f32((unsigned short)(hv.y & 0xffffu)) + bv.z;
            o.w = bf16_to_f32((unsigned short)(hv.y >> 16)) + bv.w;
            *(float4*)(hw_s + wl * 2048 + ((unsigned)(c * 16) ^ wlx)) = o;
        }
    }
    {   // stage hr bf16 -> f32 linear
        int rr = t >> 6, cc = (t & 63) * 8;
        PKu hv;
        hv.u4 = *(const uint4*)(h_rel + (size_t)(b * RR + rr) * DD + cc);
        float4 o0, o1;
        o0.x = bf16_to_f32(hv.us[0]); o0.y = bf16_to_f32(hv.us[1]);
        o0.z = bf16_to_f32(hv.us[2]); o0.w = bf16_to_f32(hv.us[3]);
        o1.x = bf16_to_f32(hv.us[4]); o1.y = bf16_to_f32(hv.us[5]);
        o1.z = bf16_to_f32(hv.us[6]); o1.w = bf16_to_f32(hv.us[7]);
        *(float4*)&hr_s[rr][cc]     = o0;
        *(float4*)&hr_s[rr][cc + 4] = o1;
    }
    {   // stage w2t, swizzled
        int n = t >> 4, cb = (t & 15) * 4;
        unsigned nx = (n & 7) << 4;
        const unsigned short* srcw = w2t + n * DD + cb * 8;
#pragma unroll
        for (int i = 0; i < 4; ++i)
            *(uint4*)(w2_s + n * 1024 + ((unsigned)((cb + i) * 16) ^ nx)) =
                *(const uint4*)(srcw + i * 8);
    }
    __syncthreads();
    int wv = t >> 6, lane = t & 63, q = lane >> 4, wl = lane & 15;
    int rr = wv;
    unsigned wlx = (wl & 7) << 4;
    f32x4 acc[2];
#pragma unroll
    for (int ni = 0; ni < 2; ++ni) acc[ni] = (f32x4){0.f, 0.f, 0.f, 0.f};

    for (int ks = 0; ks < DD / 32; ++ks) {
        int k0 = ks * 32;
        short8 bfr[2];
#pragma unroll
        for (int ni = 0; ni < 2; ++ni) {
            int n = ni * 16 + wl;
            bfr[ni] = *(const short8*)(w2_s + n * 1024 +
                        ((unsigned)((4 * ks + q) * 16) ^ wlx));
        }
        int c0 = 8 * ks + 2 * q;
        float4 f0 = *(const float4*)(hw_s + wl * 2048 + ((unsigned)(c0 * 16) ^ wlx));
        float4 f1 = *(const float4*)(hw_s + wl * 2048 + ((unsigned)((c0 + 1) * 16) ^ wlx));
        const float* hrp = &hr_s[rr][k0 + 8 * q];
        float4 h0 = *(const float4*)(hrp);
        float4 h1 = *(const float4*)(hrp + 4);
        PKu pk;
        pk.us[0] = f32_to_bf16_rne(fmaxf(f0.x + h0.x, 0.f));
        pk.us[1] = f32_to_bf16_rne(fmaxf(f0.y + h0.y, 0.f));
        pk.us[2] = f32_to_bf16_rne(fmaxf(f0.z + h0.z, 0.f));
        pk.us[3] = f32_to_bf16_rne(fmaxf(f0.w + h0.w, 0.f));
        pk.us[4] = f32_to_bf16_rne(fmaxf(f1.x + h1.x, 0.f));
        pk.us[5] = f32_to_bf16_rne(fmaxf(f1.y + h1.y, 0.f));
        pk.us[6] = f32_to_bf16_rne(fmaxf(f1.z + h1.z, 0.f));
        pk.us[7] = f32_to_bf16_rne(fmaxf(f1.w + h1.w, 0.f));
#pragma unroll
        for (int ni = 0; ni < 2; ++ni)
            acc[ni] = __builtin_amdgcn_mfma_f32_16x16x32_bf16(
                pk.s8, bfr[ni], acc[ni], 0, 0, 0);
    }
#pragma unroll
    for (int ni = 0; ni < 2; ++ni) {
        int c = ni * 16 + wl;
        if (c < CC) {
#pragma unroll
            for (int reg = 0; reg < 4; ++reg) {
                int wg = wt * 16 + 4 * q + reg;
                out_role[(size_t)((b * RR + rr) * WW + wg) * CC + c] =
                    acc[ni][reg] + b2[c];
            }
        }
    }
}

extern "C" void kernel_launch(void* const* d_in, const int* in_sizes, int n_in,
                              void* d_out, int out_size, void* d_ws, size_t ws_size,
                              hipStream_t stream) {
    const float* hidden   = (const float*)d_in[0];
    const int*   word_ids = (const int*)d_in[1];
    const int*   relpos   = (const int*)d_in[2];
    const float* w_rel    = (const float*)d_in[3];
    const float* b_rel    = (const float*)d_in[4];
    const float* w1       = (const float*)d_in[5];
    const float* b1       = (const float*)d_in[6];
    const float* w2       = (const float*)d_in[7];
    const float* b2       = (const float*)d_in[8];

    float* out0 = (float*)d_out;                    // rel_logits [16*512]
    float* out1 = out0 + BB * SS;                   // role_logits [16*8*256*27]

    unsigned short* first_hidden = (unsigned short*)d_ws;
    unsigned short* rel_hidden   = (unsigned short*)((char*)d_ws + 6291456);
    unsigned short* w1t          = (unsigned short*)((char*)d_ws + 6488064);
    unsigned short* w2t          = (unsigned short*)((char*)d_ws + 8060928);
    unsigned short* h_word       = (unsigned short*)((char*)d_ws + 8093696);
    unsigned short* h_rel        = (unsigned short*)((char*)d_ws + 12288000);

    k_front<<<2048 + 209, 256, 0, stream>>>(
        hidden, word_ids, relpos, (const float4*)w_rel, b_rel, w1, w2,
        out0, first_hidden, rel_hidden, w1t, w2t);
    k_gemm<<<dim3(8, 66), 256, 0, stream>>>(
        first_hidden, rel_hidden, w1t, h_word, h_rel);
    k_role<<<dim3(WW / 16, BB), 512, 0, stream>>>(h_word, h_rel, w2t, b1, b2, out1);
}

// Round 7
// 44.585 us; speedup vs baseline: 3.6142x; 1.0435x over previous
//
#include <hip/hip_runtime.h>
#include <hip/hip_bf16.h>

#define BB 16
#define SS 512
#define HH 768
#define RR 8
#define DD 512
#define CC 27
#define WW 256

typedef __attribute__((ext_vector_type(8))) short short8;
typedef __attribute__((ext_vector_type(4))) float f32x4;

union PKu { unsigned short us[8]; uint4 u4; short8 s8; };

__device__ __forceinline__ unsigned short f32_to_bf16_rne(float v) {
    unsigned int u = __float_as_uint(v);
    unsigned int r = u + 0x7fffu + ((u >> 16) & 1u);
    return (unsigned short)(r >> 16);
}
__device__ __forceinline__ float bf16_to_f32(unsigned short u) {
    return __uint_as_float(((unsigned int)u) << 16);
}

__device__ __forceinline__ void glds16(const void* g, void* l) {
    __builtin_amdgcn_global_load_lds(
        (const __attribute__((address_space(1))) unsigned int*)g,
        (__attribute__((address_space(3))) unsigned int*)l, 16, 0, 0);
}

// ---------------------------------------------------------------------------
// ws layout (bytes):
//   first_hidden : bf16[BB*WW][HH]   @ 0          (6291456)
//   rel_hidden   : bf16[BB*RR][HH]   @ 6291456    (196608)
//   w1t          : bf16[DD][2*HH]    @ 6488064    (1572864)
//   w2t          : bf16[32][DD]      @ 8060928    (32768)
//   h_word       : bf16[BB*WW][DD]   @ 8093696    (4194304)  (+b1 folded)
//   h_rel        : bf16[BB*RR][DD]   @ 12288000   (131072)   (no bias)
// ---------------------------------------------------------------------------

// K1: blocks 0..2047: rel_logits + first-occurrence scatter (1 wave per row)
//     blocks 2048..2256: w1t transpose / w2t / per-b zero + rel gather
__global__ __launch_bounds__(256) void k_front(
    const float* __restrict__ hidden, const int* __restrict__ word_ids,
    const int* __restrict__ relpos, const float4* __restrict__ wrel4,
    const float* __restrict__ b_rel, const float* __restrict__ w1,
    const float* __restrict__ w2, float* __restrict__ out0,
    unsigned short* __restrict__ first_hidden,
    unsigned short* __restrict__ rel_hidden,
    unsigned short* __restrict__ w1t, unsigned short* __restrict__ w2t) {
    int bid = blockIdx.x, t = threadIdx.x;
    if (bid < 2048) {
        int lane = t & 63;
        int row = bid * 4 + (t >> 6);            // b*512+s
        const float4* hid4 = (const float4*)hidden + (size_t)row * (HH / 4);
        float4 v[3];
        float acc = 0.f;
#pragma unroll
        for (int j = 0; j < 3; ++j) {
            v[j] = hid4[j * 64 + lane];
            float4 w = wrel4[j * 64 + lane];
            acc += v[j].x * w.x + v[j].y * w.y + v[j].z * w.z + v[j].w * w.w;
        }
#pragma unroll
        for (int off = 32; off > 0; off >>= 1) acc += __shfl_xor(acc, off, 64);
        if (lane == 0) out0[row] = acc + b_rel[0];
        int wid = word_ids[row];
        int s = row & (SS - 1);
        int prev = (s == 0) ? -1 : word_ids[row - 1];
        if (wid != prev) {                       // first occurrence (wave-uniform)
            int b = row >> 9;
            unsigned short* dst = first_hidden + (size_t)(b * WW + wid) * HH;
#pragma unroll
            for (int j = 0; j < 3; ++j) {
                union { unsigned short us[4]; uint2 u2; } pk;
                pk.us[0] = f32_to_bf16_rne(v[j].x);
                pk.us[1] = f32_to_bf16_rne(v[j].y);
                pk.us[2] = f32_to_bf16_rne(v[j].z);
                pk.us[3] = f32_to_bf16_rne(v[j].w);
                *(uint2*)(dst + j * 256 + lane * 4) = pk.u2;
            }
        }
        return;
    }
    int x = bid - 2048;
    if (x < 192) {              // w1 [1536][512] f32 -> w1t [512][1536] bf16
        __shared__ unsigned short tile[64][72];
        int kt = x >> 3, nt = x & 7;
        int i = t >> 2, j4 = (t & 3) * 16;
        const float* src = w1 + (size_t)(kt * 64 + i) * DD + nt * 64 + j4;
#pragma unroll
        for (int v = 0; v < 4; ++v) {
            float4 f = *(const float4*)(src + v * 4);
            tile[i][j4 + v * 4 + 0] = f32_to_bf16_rne(f.x);
            tile[i][j4 + v * 4 + 1] = f32_to_bf16_rne(f.y);
            tile[i][j4 + v * 4 + 2] = f32_to_bf16_rne(f.z);
            tile[i][j4 + v * 4 + 3] = f32_to_bf16_rne(f.w);
        }
        __syncthreads();
        int jj = t >> 2, cb = (t & 3) * 16;
        union { unsigned short us[16]; uint4 u4[2]; } ov;
#pragma unroll
        for (int v = 0; v < 16; ++v) ov.us[v] = tile[cb + v][jj];
        unsigned short* dst = w1t + (size_t)(nt * 64 + jj) * (2 * HH) + kt * 64 + cb;
        *(uint4*)(dst) = ov.u4[0];
        *(uint4*)(dst + 8) = ov.u4[1];
    } else if (x == 192) {      // w2 [512][27] -> w2t [32][512] bf16
        for (int idx = t; idx < 32 * DD; idx += 256) {
            int n = idx >> 9, k = idx & (DD - 1);
            float v = (n < CC) ? w2[(size_t)k * CC + n] : 0.f;
            w2t[n * DD + k] = f32_to_bf16_rne(v);
        }
    } else {                    // per-batch: zero absent rows + rel gather
        __shared__ int pres[WW];
        int b = x - 193;
        pres[t] = 0;
        __syncthreads();
        for (int s = t; s < SS; s += 256) pres[word_ids[b * SS + s]] = 1;
        __syncthreads();
        if (!pres[t]) {         // thread t owns word t
            uint4 z = {0u, 0u, 0u, 0u};
            unsigned short* dst = first_hidden + (size_t)(b * WW + t) * HH;
#pragma unroll 4
            for (int c = 0; c < 96; ++c) *(uint4*)(dst + c * 8) = z;
        }
        for (int idx = t; idx < 1024; idx += 256) {  // 8 rel rows x 96 chunks
            int rr = idx >> 7, c = idx & 127;
            if (c < 96) {
                int pos = relpos[b * RR + rr];
                const float* srow = hidden + (size_t)(b * SS + pos) * HH + c * 8;
                PKu pk;
#pragma unroll
                for (int e = 0; e < 8; ++e) pk.us[e] = f32_to_bf16_rne(srow[e]);
                *(uint4*)(rel_hidden + (size_t)(b * RR + rr) * HH + c * 8) = pk.u4;
            }
        }
    }
}

// K2: C = A @ w1t[:, kbase:kbase+768]^T, bf16 MFMA.
// 128x64 tile, BK=64, dbuf LDS, 4 waves 2x2 each 64x32 (4x2 frags).
// grid (8, 33): mt<32 -> h_word (bias=b1); mt==32 -> h_rel (bias=0).
__global__ __launch_bounds__(256) void k_gemm(
    const unsigned short* __restrict__ first_hidden,
    const unsigned short* __restrict__ rel_hidden,
    const unsigned short* __restrict__ w1t, const float* __restrict__ b1,
    unsigned short* __restrict__ h_word, unsigned short* __restrict__ h_rel) {
    __shared__ __align__(16) unsigned char a_s[32768];  // 2 x [128 rows][128B]
    __shared__ __align__(16) unsigned char b_s[16384];  // 2 x [64 rows][128B]
    int nt = blockIdx.x;   // 0..7
    int mt = blockIdx.y;   // 0..32
    bool isw = (mt < 32);
    const unsigned short* A = isw ? first_hidden : rel_hidden;
    unsigned short* C = isw ? h_word : h_rel;
    int kbase = isw ? 0 : HH;
    int m0 = isw ? mt * 128 : 0;
    int t = threadIdx.x;
    int wv = t >> 6, lane = t & 63;
    int wr = wv >> 1, wc = wv & 1;
    int q = lane >> 4, r = lane & 15;

    const unsigned char* aP[4];
    const unsigned char* bP[2];
    unsigned lofa[4], lofb[2];
#pragma unroll
    for (int j = 0; j < 4; ++j) {               // A: 128 rows x 8 chunks = 1024
        int ci = j * 256 + t;
        int row = ci >> 3, ch = ci & 7;
        int sc = ch ^ (row & 7);
        aP[j] = (const unsigned char*)A + (size_t)(m0 + row) * (HH * 2) + sc * 16;
        lofa[j] = ci * 16;
    }
#pragma unroll
    for (int j = 0; j < 2; ++j) {               // B: 64 rows x 8 chunks = 512
        int ci = j * 256 + t;
        int row = ci >> 3, ch = ci & 7;
        int sc = ch ^ (row & 7);
        bP[j] = (const unsigned char*)w1t + (size_t)(nt * 64 + row) * (2 * HH * 2)
                + (size_t)kbase * 2 + sc * 16;
        lofb[j] = ci * 16;
    }
    int arow[4], brow[2];
#pragma unroll
    for (int mi = 0; mi < 4; ++mi) arow[mi] = wr * 64 + mi * 16 + r;
#pragma unroll
    for (int ni = 0; ni < 2; ++ni) brow[ni] = wc * 32 + ni * 16 + r;

    f32x4 acc[4][2];
#pragma unroll
    for (int mi = 0; mi < 4; ++mi)
#pragma unroll
        for (int ni = 0; ni < 2; ++ni) acc[mi][ni] = (f32x4){0.f, 0.f, 0.f, 0.f};

    // prologue: stage kt=0 into buf 0
#pragma unroll
    for (int j = 0; j < 4; ++j) glds16(aP[j], a_s + lofa[j]);
#pragma unroll
    for (int j = 0; j < 2; ++j) glds16(bP[j], b_s + lofb[j]);
    __syncthreads();

    for (int kt = 0; kt < 12; ++kt) {
        if (kt < 11) {         // prefetch kt+1 into other buffer
            unsigned na = ((kt + 1) & 1) * 16384;
            unsigned nb = ((kt + 1) & 1) * 8192;
#pragma unroll
            for (int j = 0; j < 4; ++j) glds16(aP[j] + (kt + 1) * 128, a_s + na + lofa[j]);
#pragma unroll
            for (int j = 0; j < 2; ++j) glds16(bP[j] + (kt + 1) * 128, b_s + nb + lofb[j]);
        }
        unsigned ba = (kt & 1) * 16384;
        unsigned bb = (kt & 1) * 8192;
#pragma unroll
        for (int ks = 0; ks < 2; ++ks) {
            int c = ks * 4 + q;
            short8 bfr[2];
#pragma unroll
            for (int ni = 0; ni < 2; ++ni)
                bfr[ni] = *(const short8*)(b_s + bb + brow[ni] * 128 +
                            ((c ^ (brow[ni] & 7)) << 4));
#pragma unroll
            for (int mi = 0; mi < 4; ++mi) {
                short8 af = *(const short8*)(a_s + ba + arow[mi] * 128 +
                            ((c ^ (arow[mi] & 7)) << 4));
                acc[mi][0] = __builtin_amdgcn_mfma_f32_16x16x32_bf16(
                    af, bfr[0], acc[mi][0], 0, 0, 0);
                acc[mi][1] = __builtin_amdgcn_mfma_f32_16x16x32_bf16(
                    af, bfr[1], acc[mi][1], 0, 0, 0);
            }
        }
        __syncthreads();
    }
    float bias[2];
#pragma unroll
    for (int ni = 0; ni < 2; ++ni) {
        int n = nt * 64 + wc * 32 + ni * 16 + r;
        bias[ni] = isw ? b1[n] : 0.f;
    }
#pragma unroll
    for (int mi = 0; mi < 4; ++mi) {
        int m = m0 + wr * 64 + mi * 16 + q * 4;
#pragma unroll
        for (int ni = 0; ni < 2; ++ni) {
            int n = nt * 64 + wc * 32 + ni * 16 + r;
#pragma unroll
            for (int reg = 0; reg < 4; ++reg)
                C[(size_t)(m + reg) * DD + n] =
                    f32_to_bf16_rne(acc[mi][ni][reg] + bias[ni]);
        }
    }
}

// K3: role_logits = relu(h_word'[b,w,:]+h_rel[b,r,:]) @ w2 + b2 via MFMA.
// 512 thr = 8 waves (one r each). LDS 64KB -> 2 blocks/CU.
// hw/w2 staged via global_load_lds with pre-swizzled per-lane source.
__global__ __launch_bounds__(512) void k_role(
    const unsigned short* __restrict__ h_word, const unsigned short* __restrict__ h_rel,
    const unsigned short* __restrict__ w2t, const float* __restrict__ b2,
    float* __restrict__ out_role) {
    int wt = blockIdx.x;   // 0..15
    int b  = blockIdx.y;   // 0..15
    int t  = threadIdx.x;  // 512
    __shared__ __align__(16) unsigned char hw_s[16384];  // [16 w][512] bf16 swz
    __shared__ float hr_s[RR][DD];                       // 16 KB f32 linear
    __shared__ __align__(16) unsigned char w2_s[32768];  // [32 n][512] bf16 swz
    int wv = t >> 6, lane = t & 63;
    {   // stage hw: wave wv -> rows 2wv, 2wv+1 (glds, swizzled source chunk)
#pragma unroll
        for (int i = 0; i < 2; ++i) {
            int row = wv * 2 + i;
            const unsigned short* src = h_word +
                (size_t)(b * WW + wt * 16 + row) * DD + ((lane ^ (row & 7)) * 8);
            glds16(src, hw_s + row * 1024 + lane * 16);
        }
    }
    {   // stage w2: wave wv -> rows 4wv..4wv+3
#pragma unroll
        for (int i = 0; i < 4; ++i) {
            int row = wv * 4 + i;
            const unsigned short* src = w2t + row * DD + ((lane ^ (row & 7)) * 8);
            glds16(src, w2_s + row * 1024 + lane * 16);
        }
    }
    {   // stage hr bf16 -> f32 linear (one row per wave)
        int rr = t >> 6, c = t & 63;
        PKu hv;
        hv.u4 = *(const uint4*)(h_rel + (size_t)(b * RR + rr) * DD + c * 8);
        float4 o0, o1;
        o0.x = bf16_to_f32(hv.us[0]); o0.y = bf16_to_f32(hv.us[1]);
        o0.z = bf16_to_f32(hv.us[2]); o0.w = bf16_to_f32(hv.us[3]);
        o1.x = bf16_to_f32(hv.us[4]); o1.y = bf16_to_f32(hv.us[5]);
        o1.z = bf16_to_f32(hv.us[6]); o1.w = bf16_to_f32(hv.us[7]);
        *(float4*)&hr_s[rr][c * 8]     = o0;
        *(float4*)&hr_s[rr][c * 8 + 4] = o1;
    }
    __syncthreads();
    int q = lane >> 4, wl = lane & 15;
    int rr = wv;
    unsigned wlx = (wl & 7) << 4;
    f32x4 acc[2];
#pragma unroll
    for (int ni = 0; ni < 2; ++ni) acc[ni] = (f32x4){0.f, 0.f, 0.f, 0.f};

#pragma unroll 2
    for (int ks = 0; ks < DD / 32; ++ks) {
        int c = 4 * ks + q;
        short8 bfr[2];
#pragma unroll
        for (int ni = 0; ni < 2; ++ni) {
            int n = ni * 16 + wl;
            bfr[ni] = *(const short8*)(w2_s + n * 1024 + ((c ^ (n & 7)) << 4));
        }
        PKu hw;
        hw.u4 = *(const uint4*)(hw_s + wl * 1024 + ((unsigned)(c << 4) ^ wlx));
        const float* hrp = &hr_s[rr][ks * 32 + q * 8];
        float4 h0 = *(const float4*)(hrp);
        float4 h1 = *(const float4*)(hrp + 4);
        PKu pk;
        pk.us[0] = f32_to_bf16_rne(fmaxf(bf16_to_f32(hw.us[0]) + h0.x, 0.f));
        pk.us[1] = f32_to_bf16_rne(fmaxf(bf16_to_f32(hw.us[1]) + h0.y, 0.f));
        pk.us[2] = f32_to_bf16_rne(fmaxf(bf16_to_f32(hw.us[2]) + h0.z, 0.f));
        pk.us[3] = f32_to_bf16_rne(fmaxf(bf16_to_f32(hw.us[3]) + h0.w, 0.f));
        pk.us[4] = f32_to_bf16_rne(fmaxf(bf16_to_f32(hw.us[4]) + h1.x, 0.f));
        pk.us[5] = f32_to_bf16_rne(fmaxf(bf16_to_f32(hw.us[5]) + h1.y, 0.f));
        pk.us[6] = f32_to_bf16_rne(fmaxf(bf16_to_f32(hw.us[6]) + h1.z, 0.f));
        pk.us[7] = f32_to_bf16_rne(fmaxf(bf16_to_f32(hw.us[7]) + h1.w, 0.f));
#pragma unroll
        for (int ni = 0; ni < 2; ++ni)
            acc[ni] = __builtin_amdgcn_mfma_f32_16x16x32_bf16(
                pk.s8, bfr[ni], acc[ni], 0, 0, 0);
    }
#pragma unroll
    for (int ni = 0; ni < 2; ++ni) {
        int c = ni * 16 + wl;
        if (c < CC) {
#pragma unroll
            for (int reg = 0; reg < 4; ++reg) {
                int wg = wt * 16 + 4 * q + reg;
                out_role[(size_t)((b * RR + rr) * WW + wg) * CC + c] =
                    acc[ni][reg] + b2[c];
            }
        }
    }
}

extern "C" void kernel_launch(void* const* d_in, const int* in_sizes, int n_in,
                              void* d_out, int out_size, void* d_ws, size_t ws_size,
                              hipStream_t stream) {
    const float* hidden   = (const float*)d_in[0];
    const int*   word_ids = (const int*)d_in[1];
    const int*   relpos   = (const int*)d_in[2];
    const float* w_rel    = (const float*)d_in[3];
    const float* b_rel    = (const float*)d_in[4];
    const float* w1       = (const float*)d_in[5];
    const float* b1       = (const float*)d_in[6];
    const float* w2       = (const float*)d_in[7];
    const float* b2       = (const float*)d_in[8];

    float* out0 = (float*)d_out;                    // rel_logits [16*512]
    float* out1 = out0 + BB * SS;                   // role_logits [16*8*256*27]

    unsigned short* first_hidden = (unsigned short*)d_ws;
    unsigned short* rel_hidden   = (unsigned short*)((char*)d_ws + 6291456);
    unsigned short* w1t          = (unsigned short*)((char*)d_ws + 6488064);
    unsigned short* w2t          = (unsigned short*)((char*)d_ws + 8060928);
    unsigned short* h_word       = (unsigned short*)((char*)d_ws + 8093696);
    unsigned short* h_rel        = (unsigned short*)((char*)d_ws + 12288000);

    k_front<<<2048 + 209, 256, 0, stream>>>(
        hidden, word_ids, relpos, (const float4*)w_rel, b_rel, w1, w2,
        out0, first_hidden, rel_hidden, w1t, w2t);
    k_gemm<<<dim3(8, 33), 256, 0, stream>>>(
        first_hidden, rel_hidden, w1t, b1, h_word, h_rel);
    k_role<<<dim3(WW / 16, BB), 512, 0, stream>>>(h_word, h_rel, w2t, b2, out1);
}